// Round 2
// baseline (953.467 us; speedup 1.0000x reference)
//
#include <hip/hip_runtime.h>
#include <stdint.h>

#define HID 256

typedef __bf16 bf16x8 __attribute__((ext_vector_type(8)));
typedef float  f32x4  __attribute__((ext_vector_type(4)));

__device__ __forceinline__ unsigned short f2bf(float f){
  unsigned int x = __float_as_uint(f);
  x += 0x7FFFu + ((x >> 16) & 1u);      // RNE
  return (unsigned short)(x >> 16);
}
__device__ __forceinline__ float bf2f(unsigned int u){
  return __uint_as_float(u << 16);
}

// ---------------- CSR build ----------------
__global__ void count_kernel(const int* __restrict__ ei, int E, int* __restrict__ deg){
  int e = blockIdx.x*256 + threadIdx.x;
  if (e < E) atomicAdd(&deg[ei[E + e]], 1);
}

__global__ void dinv_kernel(const int* __restrict__ deg, float* __restrict__ dinv, int N){
  int i = blockIdx.x*256 + threadIdx.x;
  if (i < N) dinv[i] = 1.0f / sqrtf((float)(deg[i] + 1));   // +1 self loop
}

__global__ void scan1_kernel(const int* __restrict__ deg, int* __restrict__ rowptr,
                             int* __restrict__ partials, int N){
  __shared__ int sm[256];
  int t = threadIdx.x;
  int i = blockIdx.x*256 + t;
  int v = (i < N) ? deg[i] : 0;
  int acc = v;
  sm[t] = acc;
  __syncthreads();
  for (int off = 1; off < 256; off <<= 1){
    int add = (t >= off) ? sm[t - off] : 0;
    __syncthreads();
    acc += add;
    sm[t] = acc;
    __syncthreads();
  }
  if (i < N) rowptr[i] = acc - v;                 // exclusive, block-local
  if (t == 255) partials[blockIdx.x] = acc;       // block total
}

__global__ void scan2_kernel(int* __restrict__ partials, int nb){
  __shared__ int sm[256];
  int t = threadIdx.x;
  int v = (t < nb) ? partials[t] : 0;
  int acc = v;
  sm[t] = acc;
  __syncthreads();
  for (int off = 1; off < 256; off <<= 1){
    int add = (t >= off) ? sm[t - off] : 0;
    __syncthreads();
    acc += add;
    sm[t] = acc;
    __syncthreads();
  }
  if (t < nb) partials[t] = acc - v;              // exclusive block offsets
}

__global__ void scan3_kernel(int* __restrict__ rowptr, const int* __restrict__ partials,
                             int N, int E){
  int i = blockIdx.x*256 + threadIdx.x;
  if (i < N) rowptr[i] += partials[blockIdx.x];
  if (i == 0) rowptr[N] = E;
}

__global__ void scatter_kernel(const int* __restrict__ ei, int E, const int* __restrict__ rowptr,
                               int* __restrict__ fill, const float* __restrict__ dinv,
                               int* __restrict__ col, float* __restrict__ wgt){
  int e = blockIdx.x*256 + threadIdx.x;
  if (e >= E) return;
  int s = ei[e];
  int d = ei[E + e];
  int p = rowptr[d] + atomicAdd(&fill[d], 1);
  col[p] = s;
  wgt[p] = dinv[s] * dinv[d];
}

// ---------------- W -> W^T bf16 ----------------
__global__ void convW_kernel(const float* __restrict__ W1, const float* __restrict__ Wmu,
                             const float* __restrict__ Wls, unsigned short* __restrict__ Wt){
  int t = blockIdx.x*256 + threadIdx.x;
  if (t >= 3*65536) return;
  int m = t >> 16;
  int r = t & 0xFFFF;
  int n = r >> 8, k = r & 255;
  const float* W = (m == 0) ? W1 : (m == 1 ? Wmu : Wls);
  Wt[t] = f2bf(W[k*HID + n]);                     // Wt[m][n][k] = W[k][n]
}

// ---------------- aggregation: one wave per dst node ----------------
__global__ void agg_f32_to_bf16(const float* __restrict__ X, unsigned short* __restrict__ Y,
                                const int* __restrict__ rowptr, const int* __restrict__ col,
                                const float* __restrict__ wgt, const float* __restrict__ dinv,
                                int N){
  int w = (blockIdx.x * blockDim.x + threadIdx.x) >> 6;
  int lane = threadIdx.x & 63;
  if (w >= N) return;
  float sd = dinv[w];
  f32x4 acc = *((const f32x4*)(X + (size_t)w*HID) + lane) * (sd*sd);   // self loop
  int p0 = rowptr[w], p1 = rowptr[w+1];
  for (int base = p0; base < p1; base += 64){
    int idx = base + lane;
    int   sc = 0;  float wc = 0.f;
    if (idx < p1){ sc = col[idx]; wc = wgt[idx]; }
    int cnt = min(p1 - base, 64);
    for (int j = 0; j < cnt; ++j){
      int   s = __shfl(sc, j);
      float f = __shfl(wc, j);
      f32x4 u = *((const f32x4*)(X + (size_t)s*HID) + lane);
      acc += u * f;
    }
  }
  ushort4 o;
  o.x = f2bf(acc[0]); o.y = f2bf(acc[1]); o.z = f2bf(acc[2]); o.w = f2bf(acc[3]);
  *((ushort4*)(Y + (size_t)w*HID) + lane) = o;
}

__global__ void agg_bf16_to_f32(const unsigned short* __restrict__ X, float* __restrict__ Y,
                                const int* __restrict__ rowptr, const int* __restrict__ col,
                                const float* __restrict__ wgt, const float* __restrict__ dinv,
                                int N){
  int w = (blockIdx.x * blockDim.x + threadIdx.x) >> 6;
  int lane = threadIdx.x & 63;
  if (w >= N) return;
  float sd = dinv[w];
  f32x4 acc;
  {
    uint2 u = *((const uint2*)(X + (size_t)w*HID) + lane);
    float s2 = sd*sd;
    acc[0] = bf2f(u.x & 0xFFFFu) * s2;
    acc[1] = bf2f(u.x >> 16)     * s2;
    acc[2] = bf2f(u.y & 0xFFFFu) * s2;
    acc[3] = bf2f(u.y >> 16)     * s2;
  }
  int p0 = rowptr[w], p1 = rowptr[w+1];
  for (int base = p0; base < p1; base += 64){
    int idx = base + lane;
    int   sc = 0;  float wc = 0.f;
    if (idx < p1){ sc = col[idx]; wc = wgt[idx]; }
    int cnt = min(p1 - base, 64);
    for (int j = 0; j < cnt; ++j){
      int   s = __shfl(sc, j);
      float f = __shfl(wc, j);
      uint2 u = *((const uint2*)(X + (size_t)s*HID) + lane);
      acc[0] = fmaf(bf2f(u.x & 0xFFFFu), f, acc[0]);
      acc[1] = fmaf(bf2f(u.x >> 16),     f, acc[1]);
      acc[2] = fmaf(bf2f(u.y & 0xFFFFu), f, acc[2]);
      acc[3] = fmaf(bf2f(u.y >> 16),     f, acc[3]);
    }
  }
  *((f32x4*)(Y + (size_t)w*HID) + lane) = acc;
}

// ---------------- GEMM 1: h = relu(a1 @ W1 + b1), bf16 out ----------------
__global__ __launch_bounds__(256) void gemm1_kernel(const unsigned short* __restrict__ A,
    const unsigned short* __restrict__ Bt, const float* __restrict__ bias,
    unsigned short* __restrict__ H, int N){
  int r0 = blockIdx.x * 64;
  int lane = threadIdx.x & 63;
  int nw = threadIdx.x >> 6;
  int lr = lane & 15, kg = lane >> 4;
  f32x4 acc[4][4] = {};
  for (int ks = 0; ks < 8; ++ks){
    int kb = ks*32 + kg*8;
    bf16x8 af[4], bfr[4];
    #pragma unroll
    for (int rf = 0; rf < 4; ++rf){
      int row = r0 + rf*16 + lr; if (row > N-1) row = N-1;
      af[rf] = *(const bf16x8*)(A + (size_t)row*HID + kb);
    }
    #pragma unroll
    for (int cf = 0; cf < 4; ++cf){
      int c = nw*64 + cf*16 + lr;
      bfr[cf] = *(const bf16x8*)(Bt + (size_t)c*HID + kb);
    }
    #pragma unroll
    for (int rf = 0; rf < 4; ++rf)
      #pragma unroll
      for (int cf = 0; cf < 4; ++cf)
        acc[rf][cf] = __builtin_amdgcn_mfma_f32_16x16x32_bf16(af[rf], bfr[cf], acc[rf][cf], 0, 0, 0);
  }
  #pragma unroll
  for (int rf = 0; rf < 4; ++rf){
    #pragma unroll
    for (int cf = 0; cf < 4; ++cf){
      int c = nw*64 + cf*16 + lr;
      float bv = bias[c];
      #pragma unroll
      for (int i = 0; i < 4; ++i){
        int row = r0 + rf*16 + kg*4 + i;
        if (row < N){
          float hv = acc[rf][cf][i] + bv;
          H[(size_t)row*HID + c] = f2bf(fmaxf(hv, 0.0f));
        }
      }
    }
  }
}

// ---- eps: JAX PARTITIONABLE threefry2x32 (key=(0,1)) + XLA erfinv ----
// random_bits(key, 32, shape): per element i, counter=(uint64)i ->
// pair (hi32(i)=0, lo32(i)=i); bits = out0 ^ out1 (32-bit fold).
__device__ __forceinline__ unsigned int rotl32(unsigned int v, int r){
  return (v << r) | (v >> (32 - r));
}

__device__ float gauss_eps(unsigned int idxv){
  unsigned int x0 = 0u, x1 = idxv;
  const unsigned int ks0 = 0u, ks1 = 1u, ks2 = 0x1BD11BDAu ^ 0u ^ 1u;
  x0 += ks0; x1 += ks1;
#define TFR(r) { x0 += x1; x1 = rotl32(x1, r); x1 ^= x0; }
  TFR(13) TFR(15) TFR(26) TFR(6)   x0 += ks1; x1 += ks2 + 1u;
  TFR(17) TFR(29) TFR(16) TFR(24)  x0 += ks2; x1 += ks0 + 2u;
  TFR(13) TFR(15) TFR(26) TFR(6)   x0 += ks0; x1 += ks1 + 3u;
  TFR(17) TFR(29) TFR(16) TFR(24)  x0 += ks1; x1 += ks2 + 4u;
  TFR(13) TFR(15) TFR(26) TFR(6)   x0 += ks2; x1 += ks0 + 5u;
#undef TFR
  unsigned int bits = x0 ^ x1;                                  // 32-bit fold
  float f = __uint_as_float((bits >> 9) | 0x3F800000u) - 1.0f;   // [0,1)
  const float lo = -0.99999994f;                                  // nextafter(-1,0)
  float u = fmaxf(lo, fmaf(f, 2.0f, lo));                         // (hi-lo)==2.0f exactly
  // XLA ErfInv32 (Giles) polynomial
  float wv = -log1pf(-u*u);
  float p;
  if (wv < 5.0f){
    wv -= 2.5f;
    p = 2.81022636e-08f;
    p = fmaf(p, wv, 3.43273939e-07f);
    p = fmaf(p, wv, -3.5233877e-06f);
    p = fmaf(p, wv, -4.39150654e-06f);
    p = fmaf(p, wv, 0.00021858087f);
    p = fmaf(p, wv, -0.00125372503f);
    p = fmaf(p, wv, -0.00417768164f);
    p = fmaf(p, wv, 0.246640727f);
    p = fmaf(p, wv, 1.50140941f);
  } else {
    wv = sqrtf(wv) - 3.0f;
    p = -0.000200214257f;
    p = fmaf(p, wv, 0.000100950558f);
    p = fmaf(p, wv, 0.00134934322f);
    p = fmaf(p, wv, -0.00367342844f);
    p = fmaf(p, wv, 0.00573950773f);
    p = fmaf(p, wv, -0.0076224613f);
    p = fmaf(p, wv, 0.00943887047f);
    p = fmaf(p, wv, 1.00167406f);
    p = fmaf(p, wv, 2.83297682f);
  }
  return 1.4142135381698608f * (p * u);    // f32(sqrt(2)) * erfinv(u)
}

// ---- GEMM 2+3 fused + reparam sample; A2 aliases the LS output region ----
__global__ __launch_bounds__(256) void gemm23_kernel(const float* __restrict__ A2,
    const unsigned short* __restrict__ Btm, const unsigned short* __restrict__ Btl,
    const float* __restrict__ bmu, const float* __restrict__ bls,
    float* __restrict__ Z, float* __restrict__ MU, float* __restrict__ LS, int N){
  int r0 = blockIdx.x * 64;
  int lane = threadIdx.x & 63;
  int nw = threadIdx.x >> 6;
  int lr = lane & 15, kg = lane >> 4;
  f32x4 am[4][4] = {};
  f32x4 al[4][4] = {};
  for (int ks = 0; ks < 8; ++ks){
    int kb = ks*32 + kg*8;
    bf16x8 af[4], bm_[4], bl_[4];
    #pragma unroll
    for (int rf = 0; rf < 4; ++rf){
      int row = r0 + rf*16 + lr; if (row > N-1) row = N-1;
      const float* p = A2 + (size_t)row*HID + kb;
      f32x4 v0 = *(const f32x4*)p;
      f32x4 v1 = *(const f32x4*)(p + 4);
      bf16x8 a;
      #pragma unroll
      for (int j = 0; j < 4; ++j){ a[j] = (__bf16)v0[j]; a[4+j] = (__bf16)v1[j]; }
      af[rf] = a;
    }
    #pragma unroll
    for (int cf = 0; cf < 4; ++cf){
      int c = nw*64 + cf*16 + lr;
      bm_[cf] = *(const bf16x8*)(Btm + (size_t)c*HID + kb);
      bl_[cf] = *(const bf16x8*)(Btl + (size_t)c*HID + kb);
    }
    #pragma unroll
    for (int rf = 0; rf < 4; ++rf)
      #pragma unroll
      for (int cf = 0; cf < 4; ++cf){
        am[rf][cf] = __builtin_amdgcn_mfma_f32_16x16x32_bf16(af[rf], bm_[cf], am[rf][cf], 0, 0, 0);
        al[rf][cf] = __builtin_amdgcn_mfma_f32_16x16x32_bf16(af[rf], bl_[cf], al[rf][cf], 0, 0, 0);
      }
  }
  __syncthreads();   // all A2 (ls-region) reads in this block done before in-place writes
  #pragma unroll
  for (int rf = 0; rf < 4; ++rf){
    #pragma unroll
    for (int cf = 0; cf < 4; ++cf){
      int c = nw*64 + cf*16 + lr;
      float bmv = bmu[c], blv = bls[c];
      #pragma unroll
      for (int i = 0; i < 4; ++i){
        int row = r0 + rf*16 + kg*4 + i;
        if (row < N){
          size_t idx = (size_t)row*HID + c;
          float m = am[rf][cf][i] + bmv;
          float l = al[rf][cf][i] + blv;
          float e = gauss_eps((unsigned int)idx);
          Z[idx]  = m + expf(l) * e;
          MU[idx] = m;
          LS[idx] = l;
        }
      }
    }
  }
}

extern "C" void kernel_launch(void* const* d_in, const int* in_sizes, int n_in,
                              void* d_out, int out_size, void* d_ws, size_t ws_size,
                              hipStream_t stream){
  const float* x   = (const float*)d_in[0];
  const int*   ei  = (const int*)d_in[1];
  const float* W1  = (const float*)d_in[2];
  const float* b1  = (const float*)d_in[3];
  const float* Wmu = (const float*)d_in[4];
  const float* bmu = (const float*)d_in[5];
  const float* Wls = (const float*)d_in[6];
  const float* bls = (const float*)d_in[7];
  const int N = in_sizes[0] / HID;
  const int E = in_sizes[1] / 2;
  const size_t NA = ((size_t)N + 64) & ~(size_t)63;   // >= N+1, 64-aligned

  int* deg      = (int*)d_ws;
  int* fill     = deg + NA;
  int* rowptr   = fill + NA;
  int* partials = rowptr + NA;
  float* dinv   = (float*)(partials + 1024);
  int*  col     = (int*)(dinv + NA);
  float* wgt    = (float*)(col + (size_t)E);
  unsigned short* Wt = (unsigned short*)(wgt + (size_t)E);  // 3 * 65536 bf16

  float* Z  = (float*)d_out;
  float* MU = Z + (size_t)N*HID;
  float* LS = MU + (size_t)N*HID;
  unsigned short* hb  = (unsigned short*)Z;    // h (bf16) staged in z region
  unsigned short* a1b = (unsigned short*)MU;   // a1 (bf16) staged in mu region
  float* a2 = LS;                              // a2 (f32) staged in-place in ls region

  hipMemsetAsync(deg, 0, NA*2*sizeof(int), stream);          // deg + fill

  int ebl = (E + 255)/256, nbl = (N + 255)/256;
  count_kernel  <<<ebl, 256, 0, stream>>>(ei, E, deg);
  dinv_kernel   <<<nbl, 256, 0, stream>>>(deg, dinv, N);
  scan1_kernel  <<<nbl, 256, 0, stream>>>(deg, rowptr, partials, N);
  scan2_kernel  <<<1,   256, 0, stream>>>(partials, nbl);
  scan3_kernel  <<<nbl, 256, 0, stream>>>(rowptr, partials, N, E);
  scatter_kernel<<<ebl, 256, 0, stream>>>(ei, E, rowptr, fill, dinv, col, wgt);
  convW_kernel  <<<768, 256, 0, stream>>>(W1, Wmu, Wls, Wt);

  agg_f32_to_bf16<<<(N + 3)/4,  256, 0, stream>>>(x, a1b, rowptr, col, wgt, dinv, N);
  gemm1_kernel   <<<(N + 63)/64, 256, 0, stream>>>(a1b, Wt, b1, hb, N);
  agg_bf16_to_f32<<<(N + 3)/4,  256, 0, stream>>>(hb, a2, rowptr, col, wgt, dinv, N);
  gemm23_kernel  <<<(N + 63)/64, 256, 0, stream>>>(a2, Wt + 65536, Wt + 2*65536,
                                                   bmu, bls, Z, MU, LS, N);
}

// Round 3
// 940.683 us; speedup vs baseline: 1.0136x; 1.0136x over previous
//
#include <hip/hip_runtime.h>
#include <stdint.h>

#define HID 256

typedef __bf16 bf16x8 __attribute__((ext_vector_type(8)));
typedef float  f32x4  __attribute__((ext_vector_type(4)));

__device__ __forceinline__ unsigned short f2bf(float f){
  unsigned int x = __float_as_uint(f);
  x += 0x7FFFu + ((x >> 16) & 1u);      // RNE
  return (unsigned short)(x >> 16);
}
__device__ __forceinline__ float bf2f(unsigned int u){
  return __uint_as_float(u << 16);
}

// ---------------- CSR build ----------------
__global__ void count_kernel(const int* __restrict__ ei, int E, int* __restrict__ deg){
  int e = blockIdx.x*256 + threadIdx.x;
  if (e < E) atomicAdd(&deg[ei[E + e]], 1);
}

__global__ void dinv_kernel(const int* __restrict__ deg, float* __restrict__ dinv, int N){
  int i = blockIdx.x*256 + threadIdx.x;
  if (i < N) dinv[i] = 1.0f / sqrtf((float)(deg[i] + 1));   // +1 self loop
}

__global__ void scan1_kernel(const int* __restrict__ deg, int* __restrict__ rowptr,
                             int* __restrict__ partials, int N){
  __shared__ int sm[256];
  int t = threadIdx.x;
  int i = blockIdx.x*256 + t;
  int v = (i < N) ? deg[i] : 0;
  int acc = v;
  sm[t] = acc;
  __syncthreads();
  for (int off = 1; off < 256; off <<= 1){
    int add = (t >= off) ? sm[t - off] : 0;
    __syncthreads();
    acc += add;
    sm[t] = acc;
    __syncthreads();
  }
  if (i < N) rowptr[i] = acc - v;                 // exclusive, block-local
  if (t == 255) partials[blockIdx.x] = acc;       // block total
}

__global__ void scan2_kernel(int* __restrict__ partials, int nb){
  __shared__ int sm[256];
  int t = threadIdx.x;
  int v = (t < nb) ? partials[t] : 0;
  int acc = v;
  sm[t] = acc;
  __syncthreads();
  for (int off = 1; off < 256; off <<= 1){
    int add = (t >= off) ? sm[t - off] : 0;
    __syncthreads();
    acc += add;
    sm[t] = acc;
    __syncthreads();
  }
  if (t < nb) partials[t] = acc - v;              // exclusive block offsets
}

__global__ void scan3_kernel(int* __restrict__ rowptr, const int* __restrict__ partials,
                             int N, int E){
  int i = blockIdx.x*256 + threadIdx.x;
  if (i < N) rowptr[i] += partials[blockIdx.x];
  if (i == 0) rowptr[N] = E;
}

__global__ void scatter_kernel(const int* __restrict__ ei, int E, const int* __restrict__ rowptr,
                               int* __restrict__ fill, const float* __restrict__ dinv,
                               int* __restrict__ col, float* __restrict__ wgt){
  int e = blockIdx.x*256 + threadIdx.x;
  if (e >= E) return;
  int s = ei[e];
  int d = ei[E + e];
  int p = rowptr[d] + atomicAdd(&fill[d], 1);
  col[p] = s;
  wgt[p] = dinv[s] * dinv[d];
}

// ---------------- W -> W^T bf16 ----------------
// m=0: natural K order. m=1,2: K permuted by pi(p) to match gemm1's packed
// H layout: pi(p) = (p&~63) | ((p&3)<<4) | ((p>>2)&15).
__global__ void convW_kernel(const float* __restrict__ W1, const float* __restrict__ Wmu,
                             const float* __restrict__ Wls, unsigned short* __restrict__ Wt){
  int t = blockIdx.x*256 + threadIdx.x;
  if (t >= 3*65536) return;
  int m = t >> 16;
  int r = t & 0xFFFF;
  int n = r >> 8, k = r & 255;
  int ksrc = (m == 0) ? k : ((k & ~63) | ((k & 3) << 4) | ((k >> 2) & 15));
  const float* W = (m == 0) ? W1 : (m == 1 ? Wmu : Wls);
  Wt[t] = f2bf(W[ksrc*HID + n]);                  // Wt[m][n][k] = W[pi(k)][n]
}

// ---------------- aggregation: one wave per dst node ----------------
__global__ void agg_f32_to_bf16(const float* __restrict__ X, unsigned short* __restrict__ Y,
                                const int* __restrict__ rowptr, const int* __restrict__ col,
                                const float* __restrict__ wgt, const float* __restrict__ dinv,
                                int N){
  int w = (blockIdx.x * blockDim.x + threadIdx.x) >> 6;
  int lane = threadIdx.x & 63;
  if (w >= N) return;
  float sd = dinv[w];
  f32x4 acc = *((const f32x4*)(X + (size_t)w*HID) + lane) * (sd*sd);   // self loop
  int p0 = rowptr[w], p1 = rowptr[w+1];
  for (int base = p0; base < p1; base += 64){
    int idx = base + lane;
    int   sc = 0;  float wc = 0.f;
    if (idx < p1){ sc = col[idx]; wc = wgt[idx]; }
    int cnt = min(p1 - base, 64);
    for (int j = 0; j < cnt; ++j){
      int   s = __shfl(sc, j);
      float f = __shfl(wc, j);
      f32x4 u = *((const f32x4*)(X + (size_t)s*HID) + lane);
      acc += u * f;
    }
  }
  ushort4 o;
  o.x = f2bf(acc[0]); o.y = f2bf(acc[1]); o.z = f2bf(acc[2]); o.w = f2bf(acc[3]);
  *((ushort4*)(Y + (size_t)w*HID) + lane) = o;
}

// reads dense bf16 rows (256 cols), writes bf16 rows at STRIDE 512 ushorts
// (first 512B of each 1KB slot) so gemm23 can read it in-place from the LS region.
__global__ void agg_bf16_to_bf16s(const unsigned short* __restrict__ X, unsigned short* __restrict__ Y,
                                  const int* __restrict__ rowptr, const int* __restrict__ col,
                                  const float* __restrict__ wgt, const float* __restrict__ dinv,
                                  int N){
  int w = (blockIdx.x * blockDim.x + threadIdx.x) >> 6;
  int lane = threadIdx.x & 63;
  if (w >= N) return;
  float sd = dinv[w];
  f32x4 acc;
  {
    uint2 u = *((const uint2*)(X + (size_t)w*HID) + lane);
    float s2 = sd*sd;
    acc[0] = bf2f(u.x & 0xFFFFu) * s2;
    acc[1] = bf2f(u.x >> 16)     * s2;
    acc[2] = bf2f(u.y & 0xFFFFu) * s2;
    acc[3] = bf2f(u.y >> 16)     * s2;
  }
  int p0 = rowptr[w], p1 = rowptr[w+1];
  for (int base = p0; base < p1; base += 64){
    int idx = base + lane;
    int   sc = 0;  float wc = 0.f;
    if (idx < p1){ sc = col[idx]; wc = wgt[idx]; }
    int cnt = min(p1 - base, 64);
    for (int j = 0; j < cnt; ++j){
      int   s = __shfl(sc, j);
      float f = __shfl(wc, j);
      uint2 u = *((const uint2*)(X + (size_t)s*HID) + lane);
      acc[0] = fmaf(bf2f(u.x & 0xFFFFu), f, acc[0]);
      acc[1] = fmaf(bf2f(u.x >> 16),     f, acc[1]);
      acc[2] = fmaf(bf2f(u.y & 0xFFFFu), f, acc[2]);
      acc[3] = fmaf(bf2f(u.y >> 16),     f, acc[3]);
    }
  }
  ushort4 o;
  o.x = f2bf(acc[0]); o.y = f2bf(acc[1]); o.z = f2bf(acc[2]); o.w = f2bf(acc[3]);
  *((ushort4*)(Y + (size_t)w*512) + lane) = o;
}

// ---------------- GEMM 1: h = relu(a1 @ W1 + b1), bf16 out ----------------
// H stored PERMUTED: position p = nw*64+lr*4+j holds column nw*64+j*16+lr.
// Stores are ushort4 -> 4 full 128B lines per wave store.
__global__ __launch_bounds__(256) void gemm1_kernel(const unsigned short* __restrict__ A,
    const unsigned short* __restrict__ Bt, const float* __restrict__ bias,
    unsigned short* __restrict__ H, int N){
  int r0 = blockIdx.x * 64;
  int lane = threadIdx.x & 63;
  int nw = threadIdx.x >> 6;
  int lr = lane & 15, kg = lane >> 4;
  f32x4 acc[4][4] = {};
  for (int ks = 0; ks < 8; ++ks){
    int kb = ks*32 + kg*8;
    bf16x8 af[4], bfr[4];
    #pragma unroll
    for (int rf = 0; rf < 4; ++rf){
      int row = r0 + rf*16 + lr; if (row > N-1) row = N-1;
      af[rf] = *(const bf16x8*)(A + (size_t)row*HID + kb);
    }
    #pragma unroll
    for (int cf = 0; cf < 4; ++cf){
      int c = nw*64 + cf*16 + lr;
      bfr[cf] = *(const bf16x8*)(Bt + (size_t)c*HID + kb);
    }
    #pragma unroll
    for (int rf = 0; rf < 4; ++rf)
      #pragma unroll
      for (int cf = 0; cf < 4; ++cf)
        acc[rf][cf] = __builtin_amdgcn_mfma_f32_16x16x32_bf16(af[rf], bfr[cf], acc[rf][cf], 0, 0, 0);
  }
  float bv[4];
  #pragma unroll
  for (int cf = 0; cf < 4; ++cf) bv[cf] = bias[nw*64 + cf*16 + lr];
  #pragma unroll
  for (int rf = 0; rf < 4; ++rf){
    #pragma unroll
    for (int i = 0; i < 4; ++i){
      int row = r0 + rf*16 + kg*4 + i;
      if (row < N){
        ushort4 o;
        o.x = f2bf(fmaxf(acc[rf][0][i] + bv[0], 0.0f));
        o.y = f2bf(fmaxf(acc[rf][1][i] + bv[1], 0.0f));
        o.z = f2bf(fmaxf(acc[rf][2][i] + bv[2], 0.0f));
        o.w = f2bf(fmaxf(acc[rf][3][i] + bv[3], 0.0f));
        *(ushort4*)(H + (size_t)row*HID + nw*64 + lr*4) = o;
      }
    }
  }
}

// ---- eps: JAX PARTITIONABLE threefry2x32 (key=(0,1)) + XLA erfinv ----
__device__ __forceinline__ unsigned int rotl32(unsigned int v, int r){
  return (v << r) | (v >> (32 - r));
}

__device__ float gauss_eps(unsigned int idxv){
  unsigned int x0 = 0u, x1 = idxv;
  const unsigned int ks0 = 0u, ks1 = 1u, ks2 = 0x1BD11BDAu ^ 0u ^ 1u;
  x0 += ks0; x1 += ks1;
#define TFR(r) { x0 += x1; x1 = rotl32(x1, r); x1 ^= x0; }
  TFR(13) TFR(15) TFR(26) TFR(6)   x0 += ks1; x1 += ks2 + 1u;
  TFR(17) TFR(29) TFR(16) TFR(24)  x0 += ks2; x1 += ks0 + 2u;
  TFR(13) TFR(15) TFR(26) TFR(6)   x0 += ks0; x1 += ks1 + 3u;
  TFR(17) TFR(29) TFR(16) TFR(24)  x0 += ks1; x1 += ks2 + 4u;
  TFR(13) TFR(15) TFR(26) TFR(6)   x0 += ks2; x1 += ks0 + 5u;
#undef TFR
  unsigned int bits = x0 ^ x1;                                   // 32-bit fold
  float f = __uint_as_float((bits >> 9) | 0x3F800000u) - 1.0f;   // [0,1)
  const float lo = -0.99999994f;                                  // nextafter(-1,0)
  float u = fmaxf(lo, fmaf(f, 2.0f, lo));                         // (hi-lo)==2.0f exactly
  float wv = -log1pf(-u*u);
  float p;
  if (wv < 5.0f){
    wv -= 2.5f;
    p = 2.81022636e-08f;
    p = fmaf(p, wv, 3.43273939e-07f);
    p = fmaf(p, wv, -3.5233877e-06f);
    p = fmaf(p, wv, -4.39150654e-06f);
    p = fmaf(p, wv, 0.00021858087f);
    p = fmaf(p, wv, -0.00125372503f);
    p = fmaf(p, wv, -0.00417768164f);
    p = fmaf(p, wv, 0.246640727f);
    p = fmaf(p, wv, 1.50140941f);
  } else {
    wv = sqrtf(wv) - 3.0f;
    p = -0.000200214257f;
    p = fmaf(p, wv, 0.000100950558f);
    p = fmaf(p, wv, 0.00134934322f);
    p = fmaf(p, wv, -0.00367342844f);
    p = fmaf(p, wv, 0.00573950773f);
    p = fmaf(p, wv, -0.0076224613f);
    p = fmaf(p, wv, 0.00943887047f);
    p = fmaf(p, wv, 1.00167406f);
    p = fmaf(p, wv, 2.83297682f);
  }
  return 1.4142135381698608f * (p * u);    // f32(sqrt(2)) * erfinv(u)
}

// ---- GEMM 2+3 fused + reparam; A2b (bf16, stride-512 rows) aliases LS region.
// LDS-staged epilogue: full-line f32x4 stores for Z/MU/LS.
__global__ __launch_bounds__(256) void gemm23_kernel(const unsigned short* __restrict__ A2b,
    const unsigned short* __restrict__ Btm, const unsigned short* __restrict__ Btl,
    const float* __restrict__ bmu, const float* __restrict__ bls,
    float* __restrict__ Z, float* __restrict__ MU, float* __restrict__ LS, int N){
  __shared__ float sml[2][16][260];     // stride 260: 16B-aligned rows, 2-way banks (free)
  int r0 = blockIdx.x * 64;
  int lane = threadIdx.x & 63;
  int nw = threadIdx.x >> 6;
  int lr = lane & 15, kg = lane >> 4;
  f32x4 am[4][4] = {};
  f32x4 al[4][4] = {};
  for (int ks = 0; ks < 8; ++ks){
    int kb = ks*32 + kg*8;
    bf16x8 af[4], bm_[4], bl_[4];
    #pragma unroll
    for (int rf = 0; rf < 4; ++rf){
      int row = r0 + rf*16 + lr; if (row > N-1) row = N-1;
      af[rf] = *(const bf16x8*)(A2b + (size_t)row*512 + kb);
    }
    #pragma unroll
    for (int cf = 0; cf < 4; ++cf){
      int c = nw*64 + cf*16 + lr;
      bm_[cf] = *(const bf16x8*)(Btm + (size_t)c*HID + kb);
      bl_[cf] = *(const bf16x8*)(Btl + (size_t)c*HID + kb);
    }
    #pragma unroll
    for (int rf = 0; rf < 4; ++rf)
      #pragma unroll
      for (int cf = 0; cf < 4; ++cf){
        am[rf][cf] = __builtin_amdgcn_mfma_f32_16x16x32_bf16(af[rf], bm_[cf], am[rf][cf], 0, 0, 0);
        al[rf][cf] = __builtin_amdgcn_mfma_f32_16x16x32_bf16(af[rf], bl_[cf], al[rf][cf], 0, 0, 0);
      }
  }
  f32x4 bm4 = *(const f32x4*)(bmu + lane*4);
  f32x4 bl4 = *(const f32x4*)(bls + lane*4);
  for (int rf = 0; rf < 4; ++rf){
    // stage this rf-slice (16 rows x 256 cols) of m,l into LDS
    #pragma unroll
    for (int cf = 0; cf < 4; ++cf){
      int c = nw*64 + cf*16 + lr;
      #pragma unroll
      for (int i = 0; i < 4; ++i){
        int rl = kg*4 + i;
        sml[0][rl][c] = am[rf][cf][i];
        sml[1][rl][c] = al[rf][cf][i];
      }
    }
    __syncthreads();   // (rf=0: also guarantees all A2b reads precede LS writes)
    #pragma unroll
    for (int rr = 0; rr < 4; ++rr){
      int rl = nw*4 + rr;
      int row = r0 + rf*16 + rl;
      if (row < N){
        f32x4 m4 = *(const f32x4*)&sml[0][rl][lane*4];
        f32x4 l4 = *(const f32x4*)&sml[1][rl][lane*4];
        m4 += bm4;
        l4 += bl4;
        size_t base = (size_t)row*HID + lane*4;
        f32x4 z4;
        #pragma unroll
        for (int j = 0; j < 4; ++j){
          float e = gauss_eps((unsigned int)(base + j));
          z4[j] = m4[j] + expf(l4[j]) * e;
        }
        *(f32x4*)(Z  + base) = z4;
        *(f32x4*)(MU + base) = m4;
        *(f32x4*)(LS + base) = l4;
      }
    }
    __syncthreads();   // LDS reuse fence before next rf overwrites
  }
}

extern "C" void kernel_launch(void* const* d_in, const int* in_sizes, int n_in,
                              void* d_out, int out_size, void* d_ws, size_t ws_size,
                              hipStream_t stream){
  const float* x   = (const float*)d_in[0];
  const int*   ei  = (const int*)d_in[1];
  const float* W1  = (const float*)d_in[2];
  const float* b1  = (const float*)d_in[3];
  const float* Wmu = (const float*)d_in[4];
  const float* bmu = (const float*)d_in[5];
  const float* Wls = (const float*)d_in[6];
  const float* bls = (const float*)d_in[7];
  const int N = in_sizes[0] / HID;
  const int E = in_sizes[1] / 2;
  const size_t NA = ((size_t)N + 64) & ~(size_t)63;   // >= N+1, 64-aligned

  int* deg      = (int*)d_ws;
  int* fill     = deg + NA;
  int* rowptr   = fill + NA;
  int* partials = rowptr + NA;
  float* dinv   = (float*)(partials + 1024);
  int*  col     = (int*)(dinv + NA);
  float* wgt    = (float*)(col + (size_t)E);
  unsigned short* Wt = (unsigned short*)(wgt + (size_t)E);  // 3 * 65536 bf16

  float* Z  = (float*)d_out;
  float* MU = Z + (size_t)N*HID;
  float* LS = MU + (size_t)N*HID;
  unsigned short* hb  = (unsigned short*)Z;    // h (bf16, permuted cols) in z region
  unsigned short* a1b = (unsigned short*)MU;   // a1 (bf16) staged in mu region
  unsigned short* a2b = (unsigned short*)LS;   // a2 (bf16, stride-512 rows) in ls region

  hipMemsetAsync(deg, 0, NA*2*sizeof(int), stream);          // deg + fill

  int ebl = (E + 255)/256, nbl = (N + 255)/256;
  count_kernel  <<<ebl, 256, 0, stream>>>(ei, E, deg);
  dinv_kernel   <<<nbl, 256, 0, stream>>>(deg, dinv, N);
  scan1_kernel  <<<nbl, 256, 0, stream>>>(deg, rowptr, partials, N);
  scan2_kernel  <<<1,   256, 0, stream>>>(partials, nbl);
  scan3_kernel  <<<nbl, 256, 0, stream>>>(rowptr, partials, N, E);
  scatter_kernel<<<ebl, 256, 0, stream>>>(ei, E, rowptr, fill, dinv, col, wgt);
  convW_kernel  <<<768, 256, 0, stream>>>(W1, Wmu, Wls, Wt);

  agg_f32_to_bf16 <<<(N + 3)/4,  256, 0, stream>>>(x, a1b, rowptr, col, wgt, dinv, N);
  gemm1_kernel    <<<(N + 63)/64, 256, 0, stream>>>(a1b, Wt, b1, hb, N);
  agg_bf16_to_bf16s<<<(N + 3)/4, 256, 0, stream>>>(hb, a2b, rowptr, col, wgt, dinv, N);
  gemm23_kernel   <<<(N + 63)/64, 256, 0, stream>>>(a2b, Wt + 65536, Wt + 2*65536,
                                                    bmu, bls, Z, MU, LS, N);
}

// Round 4
// 793.781 us; speedup vs baseline: 1.2012x; 1.1851x over previous
//
#include <hip/hip_runtime.h>
#include <stdint.h>

#define HID 256

typedef __bf16 bf16x8 __attribute__((ext_vector_type(8)));
typedef float  f32x4  __attribute__((ext_vector_type(4)));
typedef unsigned int uint4v __attribute__((ext_vector_type(4)));

__device__ __forceinline__ unsigned short f2bf(float f){
  unsigned int x = __float_as_uint(f);
  x += 0x7FFFu + ((x >> 16) & 1u);      // RNE
  return (unsigned short)(x >> 16);
}
__device__ __forceinline__ float bf2f(unsigned int u){
  return __uint_as_float(u << 16);
}
__device__ __forceinline__ bf16x8 ntload8(const unsigned short* p){
  uint4v t = __builtin_nontemporal_load((const uint4v*)p);
  return __builtin_bit_cast(bf16x8, t);
}

// ---------------- CSR build ----------------
__global__ void count_kernel(const int* __restrict__ ei, int E, int* __restrict__ deg){
  int e = blockIdx.x*256 + threadIdx.x;
  if (e < E) atomicAdd(&deg[ei[E + e]], 1);
}

__global__ void dinv_kernel(const int* __restrict__ deg, float* __restrict__ dinv, int N){
  int i = blockIdx.x*256 + threadIdx.x;
  if (i < N) dinv[i] = 1.0f / sqrtf((float)(deg[i] + 1));   // +1 self loop
}

__global__ void scan1_kernel(const int* __restrict__ deg, int* __restrict__ rowptr,
                             int* __restrict__ partials, int N){
  __shared__ int sm[256];
  int t = threadIdx.x;
  int i = blockIdx.x*256 + t;
  int v = (i < N) ? deg[i] : 0;
  int acc = v;
  sm[t] = acc;
  __syncthreads();
  for (int off = 1; off < 256; off <<= 1){
    int add = (t >= off) ? sm[t - off] : 0;
    __syncthreads();
    acc += add;
    sm[t] = acc;
    __syncthreads();
  }
  if (i < N) rowptr[i] = acc - v;                 // exclusive, block-local
  if (t == 255) partials[blockIdx.x] = acc;       // block total
}

__global__ void scan2_kernel(int* __restrict__ partials, int nb){
  __shared__ int sm[256];
  int t = threadIdx.x;
  int v = (t < nb) ? partials[t] : 0;
  int acc = v;
  sm[t] = acc;
  __syncthreads();
  for (int off = 1; off < 256; off <<= 1){
    int add = (t >= off) ? sm[t - off] : 0;
    __syncthreads();
    acc += add;
    sm[t] = acc;
    __syncthreads();
  }
  if (t < nb) partials[t] = acc - v;              // exclusive block offsets
}

__global__ void scan3_kernel(int* __restrict__ rowptr, const int* __restrict__ partials,
                             int N, int E){
  int i = blockIdx.x*256 + threadIdx.x;
  if (i < N) rowptr[i] += partials[blockIdx.x];
  if (i == 0) rowptr[N] = E;
}

__global__ void scatter_kernel(const int* __restrict__ ei, int E, const int* __restrict__ rowptr,
                               int* __restrict__ fill, const float* __restrict__ dinv,
                               int* __restrict__ col, float* __restrict__ wgt){
  int e = blockIdx.x*256 + threadIdx.x;
  if (e >= E) return;
  int s = ei[e];
  int d = ei[E + e];
  int p = rowptr[d] + atomicAdd(&fill[d], 1);
  col[p] = s;
  wgt[p] = dinv[s] * dinv[d];
}

// ---------------- x (f32) -> xb (bf16), 8 elems/thread ----------------
__global__ void convX_kernel(const float* __restrict__ x, unsigned short* __restrict__ xb, int total8){
  int t = blockIdx.x*256 + threadIdx.x;
  if (t >= total8) return;
  const float* p = x + (size_t)t*8;
  f32x4 a = *(const f32x4*)p;
  f32x4 b = *(const f32x4*)(p + 4);
  ushort4 o0, o1;
  o0.x = f2bf(a[0]); o0.y = f2bf(a[1]); o0.z = f2bf(a[2]); o0.w = f2bf(a[3]);
  o1.x = f2bf(b[0]); o1.y = f2bf(b[1]); o1.z = f2bf(b[2]); o1.w = f2bf(b[3]);
  ushort4* q = (ushort4*)(xb + (size_t)t*8);
  q[0] = o0; q[1] = o1;
}

// ---------------- W -> W^T bf16 ----------------
// m=0: natural K order. m=1,2: K permuted by pi(p) to match gemm1's packed
// H layout: pi(p) = (p&~63) | ((p&3)<<4) | ((p>>2)&15).
__global__ void convW_kernel(const float* __restrict__ W1, const float* __restrict__ Wmu,
                             const float* __restrict__ Wls, unsigned short* __restrict__ Wt){
  int t = blockIdx.x*256 + threadIdx.x;
  if (t >= 3*65536) return;
  int m = t >> 16;
  int r = t & 0xFFFF;
  int n = r >> 8, k = r & 255;
  int ksrc = (m == 0) ? k : ((k & ~63) | ((k & 3) << 4) | ((k >> 2) & 15));
  const float* W = (m == 0) ? W1 : (m == 1 ? Wmu : Wls);
  Wt[t] = f2bf(W[ksrc*HID + n]);                  // Wt[m][n][k] = W[pi(k)][n]
}

// -------- unified bf16 aggregation: one wave per dst node --------
// in rows at stride sin (ushorts), out rows at stride sout (ushorts), 256 cols.
__global__ void agg_bf16(const unsigned short* __restrict__ X, unsigned short* __restrict__ Y,
                         const int* __restrict__ rowptr, const int* __restrict__ col,
                         const float* __restrict__ wgt, const float* __restrict__ dinv,
                         int N, int sin, int sout){
  int w = (blockIdx.x * blockDim.x + threadIdx.x) >> 6;
  int lane = threadIdx.x & 63;
  if (w >= N) return;
  float sd = dinv[w];
  f32x4 acc;
  {
    uint2 u = *((const uint2*)(X + (size_t)w*sin) + lane);
    float s2 = sd*sd;
    acc[0] = bf2f(u.x & 0xFFFFu) * s2;
    acc[1] = bf2f(u.x >> 16)     * s2;
    acc[2] = bf2f(u.y & 0xFFFFu) * s2;
    acc[3] = bf2f(u.y >> 16)     * s2;
  }
  int p0 = rowptr[w], p1 = rowptr[w+1];
  for (int base = p0; base < p1; base += 64){
    int idx = base + lane;
    int   sc = 0;  float wc = 0.f;
    if (idx < p1){ sc = col[idx]; wc = wgt[idx]; }
    int cnt = min(p1 - base, 64);
    for (int j = 0; j < cnt; ++j){
      int   s = __shfl(sc, j);
      float f = __shfl(wc, j);
      uint2 u = *((const uint2*)(X + (size_t)s*sin) + lane);
      acc[0] = fmaf(bf2f(u.x & 0xFFFFu), f, acc[0]);
      acc[1] = fmaf(bf2f(u.x >> 16),     f, acc[1]);
      acc[2] = fmaf(bf2f(u.y & 0xFFFFu), f, acc[2]);
      acc[3] = fmaf(bf2f(u.y >> 16),     f, acc[3]);
    }
  }
  ushort4 o;
  o.x = f2bf(acc[0]); o.y = f2bf(acc[1]); o.z = f2bf(acc[2]); o.w = f2bf(acc[3]);
  *((ushort4*)(Y + (size_t)w*sout) + lane) = o;
}

// ---------------- GEMM 1: h = relu(a1 @ W1 + b1), bf16 out, BM=32 ----------------
// H stored PERMUTED: position p = nw*64+lr*4+j holds column nw*64+j*16+lr.
__global__ __launch_bounds__(256, 4) void gemm1_kernel(const unsigned short* __restrict__ A,
    const unsigned short* __restrict__ Bt, const float* __restrict__ bias,
    unsigned short* __restrict__ H, int N){
  int r0 = blockIdx.x * 32;
  int lane = threadIdx.x & 63;
  int nw = threadIdx.x >> 6;
  int lr = lane & 15, kg = lane >> 4;
  f32x4 acc[2][4] = {};
  for (int ks = 0; ks < 8; ++ks){
    int kb = ks*32 + kg*8;
    bf16x8 af[2];
    #pragma unroll
    for (int rf = 0; rf < 2; ++rf){
      int row = r0 + rf*16 + lr; if (row > N-1) row = N-1;
      af[rf] = *(const bf16x8*)(A + (size_t)row*HID + kb);
    }
    #pragma unroll
    for (int cf = 0; cf < 4; ++cf){
      int c = nw*64 + cf*16 + lr;
      bf16x8 bfr = *(const bf16x8*)(Bt + (size_t)c*HID + kb);
      acc[0][cf] = __builtin_amdgcn_mfma_f32_16x16x32_bf16(af[0], bfr, acc[0][cf], 0, 0, 0);
      acc[1][cf] = __builtin_amdgcn_mfma_f32_16x16x32_bf16(af[1], bfr, acc[1][cf], 0, 0, 0);
    }
  }
  float bv[4];
  #pragma unroll
  for (int cf = 0; cf < 4; ++cf) bv[cf] = bias[nw*64 + cf*16 + lr];
  #pragma unroll
  for (int rf = 0; rf < 2; ++rf){
    #pragma unroll
    for (int i = 0; i < 4; ++i){
      int row = r0 + rf*16 + kg*4 + i;
      if (row < N){
        ushort4 o;
        o.x = f2bf(fmaxf(acc[rf][0][i] + bv[0], 0.0f));
        o.y = f2bf(fmaxf(acc[rf][1][i] + bv[1], 0.0f));
        o.z = f2bf(fmaxf(acc[rf][2][i] + bv[2], 0.0f));
        o.w = f2bf(fmaxf(acc[rf][3][i] + bv[3], 0.0f));
        *(ushort4*)(H + (size_t)row*HID + nw*64 + lr*4) = o;
      }
    }
  }
}

// ---- eps: JAX PARTITIONABLE threefry2x32 (key=(0,1)) + XLA erfinv ----
__device__ __forceinline__ unsigned int rotl32(unsigned int v, int r){
  return (v << r) | (v >> (32 - r));
}

__device__ __forceinline__ float gauss_eps(unsigned int idxv){
  unsigned int x0 = 0u, x1 = idxv;
  const unsigned int ks0 = 0u, ks1 = 1u, ks2 = 0x1BD11BDAu ^ 0u ^ 1u;
  x0 += ks0; x1 += ks1;
#define TFR(r) { x0 += x1; x1 = rotl32(x1, r); x1 ^= x0; }
  TFR(13) TFR(15) TFR(26) TFR(6)   x0 += ks1; x1 += ks2 + 1u;
  TFR(17) TFR(29) TFR(16) TFR(24)  x0 += ks2; x1 += ks0 + 2u;
  TFR(13) TFR(15) TFR(26) TFR(6)   x0 += ks0; x1 += ks1 + 3u;
  TFR(17) TFR(29) TFR(16) TFR(24)  x0 += ks1; x1 += ks2 + 4u;
  TFR(13) TFR(15) TFR(26) TFR(6)   x0 += ks2; x1 += ks0 + 5u;
#undef TFR
  unsigned int bits = x0 ^ x1;                                   // 32-bit fold
  float f = __uint_as_float((bits >> 9) | 0x3F800000u) - 1.0f;   // [0,1)
  const float lo = -0.99999994f;                                  // nextafter(-1,0)
  float u = fmaxf(lo, fmaf(f, 2.0f, lo));                         // (hi-lo)==2.0f exactly
  // w = -log1p(-u^2), via HW log2: fmaf keeps 1-u*u single-rounded (>0 for |u|<1)
  float t = fmaf(-u, u, 1.0f);
  float wv = -0.69314718056f * __builtin_amdgcn_logf(t);
  float p;
  if (wv < 5.0f){
    wv -= 2.5f;
    p = 2.81022636e-08f;
    p = fmaf(p, wv, 3.43273939e-07f);
    p = fmaf(p, wv, -3.5233877e-06f);
    p = fmaf(p, wv, -4.39150654e-06f);
    p = fmaf(p, wv, 0.00021858087f);
    p = fmaf(p, wv, -0.00125372503f);
    p = fmaf(p, wv, -0.00417768164f);
    p = fmaf(p, wv, 0.246640727f);
    p = fmaf(p, wv, 1.50140941f);
  } else {
    wv = sqrtf(wv) - 3.0f;
    p = -0.000200214257f;
    p = fmaf(p, wv, 0.000100950558f);
    p = fmaf(p, wv, 0.00134934322f);
    p = fmaf(p, wv, -0.00367342844f);
    p = fmaf(p, wv, 0.00573950773f);
    p = fmaf(p, wv, -0.0076224613f);
    p = fmaf(p, wv, 0.00943887047f);
    p = fmaf(p, wv, 1.00167406f);
    p = fmaf(p, wv, 2.83297682f);
  }
  return 1.4142135381698608f * (p * u);    // f32(sqrt(2)) * erfinv(u)
}

// ---- GEMM 2+3 fused + reparam, BM=32; A2b (bf16, stride-512 rows) aliases LS.
// LDS-staged epilogue, non-temporal full-line f32x4 stores for Z/MU/LS.
__global__ __launch_bounds__(256, 4) void gemm23_kernel(const unsigned short* __restrict__ A2b,
    const unsigned short* __restrict__ Btm, const unsigned short* __restrict__ Btl,
    const float* __restrict__ bmu, const float* __restrict__ bls,
    float* __restrict__ Z, float* __restrict__ MU, float* __restrict__ LS, int N){
  __shared__ float sml[2][16][260];     // 33280 B
  int r0 = blockIdx.x * 32;
  int lane = threadIdx.x & 63;
  int nw = threadIdx.x >> 6;
  int lr = lane & 15, kg = lane >> 4;
  f32x4 am[2][4] = {};
  f32x4 al[2][4] = {};
  for (int ks = 0; ks < 8; ++ks){
    int kb = ks*32 + kg*8;
    bf16x8 af[2];
    #pragma unroll
    for (int rf = 0; rf < 2; ++rf){
      int row = r0 + rf*16 + lr; if (row > N-1) row = N-1;
      af[rf] = ntload8(A2b + (size_t)row*512 + kb);
    }
    #pragma unroll
    for (int cf = 0; cf < 4; ++cf){
      int c = nw*64 + cf*16 + lr;
      bf16x8 bm_ = *(const bf16x8*)(Btm + (size_t)c*HID + kb);
      bf16x8 bl_ = *(const bf16x8*)(Btl + (size_t)c*HID + kb);
      am[0][cf] = __builtin_amdgcn_mfma_f32_16x16x32_bf16(af[0], bm_, am[0][cf], 0, 0, 0);
      am[1][cf] = __builtin_amdgcn_mfma_f32_16x16x32_bf16(af[1], bm_, am[1][cf], 0, 0, 0);
      al[0][cf] = __builtin_amdgcn_mfma_f32_16x16x32_bf16(af[0], bl_, al[0][cf], 0, 0, 0);
      al[1][cf] = __builtin_amdgcn_mfma_f32_16x16x32_bf16(af[1], bl_, al[1][cf], 0, 0, 0);
    }
  }
  f32x4 bm4 = *(const f32x4*)(bmu + lane*4);
  f32x4 bl4 = *(const f32x4*)(bls + lane*4);
  for (int rf = 0; rf < 2; ++rf){
    #pragma unroll
    for (int cf = 0; cf < 4; ++cf){
      int c = nw*64 + cf*16 + lr;
      #pragma unroll
      for (int i = 0; i < 4; ++i){
        int rl = kg*4 + i;
        sml[0][rl][c] = am[rf][cf][i];
        sml[1][rl][c] = al[rf][cf][i];
      }
    }
    __syncthreads();   // (rf=0: all A2b reads precede in-place LS writes)
    #pragma unroll
    for (int rr = 0; rr < 4; ++rr){
      int rl = nw*4 + rr;
      int row = r0 + rf*16 + rl;
      if (row < N){
        f32x4 m4 = *(const f32x4*)&sml[0][rl][lane*4];
        f32x4 l4 = *(const f32x4*)&sml[1][rl][lane*4];
        m4 += bm4;
        l4 += bl4;
        size_t base = (size_t)row*HID + lane*4;
        f32x4 z4;
        #pragma unroll
        for (int j = 0; j < 4; ++j){
          float e = gauss_eps((unsigned int)(base + j));
          float s = __builtin_amdgcn_exp2f(l4[j] * 1.44269504f);
          z4[j] = fmaf(s, e, m4[j]);
        }
        __builtin_nontemporal_store(z4, (f32x4*)(Z  + base));
        __builtin_nontemporal_store(m4, (f32x4*)(MU + base));
        __builtin_nontemporal_store(l4, (f32x4*)(LS + base));
      }
    }
    __syncthreads();   // LDS reuse fence before next rf overwrites
  }
}

extern "C" void kernel_launch(void* const* d_in, const int* in_sizes, int n_in,
                              void* d_out, int out_size, void* d_ws, size_t ws_size,
                              hipStream_t stream){
  const float* x   = (const float*)d_in[0];
  const int*   ei  = (const int*)d_in[1];
  const float* W1  = (const float*)d_in[2];
  const float* b1  = (const float*)d_in[3];
  const float* Wmu = (const float*)d_in[4];
  const float* bmu = (const float*)d_in[5];
  const float* Wls = (const float*)d_in[6];
  const float* bls = (const float*)d_in[7];
  const int N = in_sizes[0] / HID;
  const int E = in_sizes[1] / 2;
  const size_t NA = ((size_t)N + 64) & ~(size_t)63;   // >= N+1, 64-aligned

  int* deg      = (int*)d_ws;
  int* fill     = deg + NA;
  int* rowptr   = fill + NA;
  int* partials = rowptr + NA;
  float* dinv   = (float*)(partials + 1024);
  int*  col     = (int*)(dinv + NA);
  float* wgt    = (float*)(col + (size_t)E);
  unsigned short* Wt = (unsigned short*)(wgt + (size_t)E);  // 3 * 65536 bf16

  float* Z  = (float*)d_out;
  float* MU = Z + (size_t)N*HID;
  float* LS = MU + (size_t)N*HID;
  unsigned short* hb  = (unsigned short*)Z;              // h (bf16, permuted cols), Z 1st half
  unsigned short* xb  = (unsigned short*)Z + (size_t)N*HID;  // x (bf16), Z 2nd half
  unsigned short* a1b = (unsigned short*)MU;             // a1 (bf16) staged in mu region
  unsigned short* a2b = (unsigned short*)LS;             // a2 (bf16, stride-512 rows) in ls region

  hipMemsetAsync(deg, 0, NA*2*sizeof(int), stream);      // deg + fill

  int ebl = (E + 255)/256, nbl = (N + 255)/256;
  count_kernel  <<<ebl, 256, 0, stream>>>(ei, E, deg);
  dinv_kernel   <<<nbl, 256, 0, stream>>>(deg, dinv, N);
  scan1_kernel  <<<nbl, 256, 0, stream>>>(deg, rowptr, partials, N);
  scan2_kernel  <<<1,   256, 0, stream>>>(partials, nbl);
  scan3_kernel  <<<nbl, 256, 0, stream>>>(rowptr, partials, N, E);
  scatter_kernel<<<ebl, 256, 0, stream>>>(ei, E, rowptr, fill, dinv, col, wgt);
  convW_kernel  <<<768, 256, 0, stream>>>(W1, Wmu, Wls, Wt);
  convX_kernel  <<<(N*HID/8 + 255)/256, 256, 0, stream>>>(x, xb, N*HID/8);

  agg_bf16    <<<(N + 3)/4,  256, 0, stream>>>(xb, a1b, rowptr, col, wgt, dinv, N, 256, 256);
  gemm1_kernel<<<(N + 31)/32, 256, 0, stream>>>(a1b, Wt, b1, hb, N);
  agg_bf16    <<<(N + 3)/4,  256, 0, stream>>>(hb, a2b, rowptr, col, wgt, dinv, N, 256, 512);
  gemm23_kernel<<<(N + 31)/32, 256, 0, stream>>>(a2b, Wt + 65536, Wt + 2*65536,
                                                 bmu, bls, Z, MU, LS, N);
}